// Round 5
// baseline (254.327 us; speedup 1.0000x reference)
//
#include <hip/hip_runtime.h>
#include <stdint.h>

// Problem constants
#define BB 2
#define SS 2048
#define DD 1024
#define HH 16
#define DHH 64

typedef __bf16 bf16_t;
typedef bf16_t bf16x8 __attribute__((ext_vector_type(8)));
typedef float f32x4 __attribute__((ext_vector_type(4)));
typedef short s16x4 __attribute__((ext_vector_type(4)));

union FragU { uint4 u; bf16x8 b; };
union Frag4U { uint2 u; s16x4 s; };

#if __has_builtin(__builtin_amdgcn_exp2f)
#define EXP2(x) __builtin_amdgcn_exp2f(x)
#else
#define EXP2(x) exp2f(x)
#endif

__device__ __forceinline__ unsigned short f2bf(float f) {
  union { float f; unsigned int u; } x; x.f = f;
  unsigned int u = x.u;
  return (unsigned short)((u + 0x7FFFu + ((u >> 16) & 1u)) >> 16);  // RNE
}

__device__ __forceinline__ uint2 pack4(float4 v) {
  uint2 r;
  r.x = (unsigned)f2bf(v.x) | ((unsigned)f2bf(v.y) << 16);
  r.y = (unsigned)f2bf(v.z) | ((unsigned)f2bf(v.w) << 16);
  return r;
}

__device__ __forceinline__ bf16x8 ldsFrag(const unsigned short* s, int idx) {
  FragU f;
  f.u = *reinterpret_cast<const uint4*>(s + idx);
  return f.b;
}

// async global -> LDS, 16 bytes per lane. LDS dest = wave-uniform base + lane*16.
__device__ __forceinline__ void gload_lds16(const unsigned short* g, unsigned short* s) {
  __builtin_amdgcn_global_load_lds(
      (const __attribute__((address_space(1))) unsigned int*)g,
      (__attribute__((address_space(3))) unsigned int*)s, 16, 0, 0);
}

#define MFMA16(a, b, c) __builtin_amdgcn_mfma_f32_16x16x32_bf16((a), (b), (c), 0, 0, 0)
#define MFMA16K16(a, b, c) __builtin_amdgcn_mfma_f32_16x16x16bf16_1k((a), (b), (c), 0, 0, 0)

// ---- fp32 -> bf16 convert: activations (z=0..2) + weights (z=3..6) + mask pad (z=7) ----
// Wq (z==3) pre-scaled by (1/8)*log2(e) (score scale + exp2-domain fold).
__global__ __launch_bounds__(256) void convert_kernel(
    const float* __restrict__ q, const float* __restrict__ k, const float* __restrict__ v,
    const float* __restrict__ Wq, const float* __restrict__ Wk,
    const float* __restrict__ Wv, const float* __restrict__ Wo,
    const int* __restrict__ mask,
    unsigned short* __restrict__ Ab, unsigned short* __restrict__ Wb,
    float* __restrict__ Mf) {
  const int z = blockIdx.y;
  if (z == 7) {  // mask -> additive pad floats (BB*SS = 4096 elements)
    if (blockIdx.x >= 4) return;
    const size_t base = (size_t)blockIdx.x * 1024 + (size_t)threadIdx.x * 4;
    int4 m4 = *reinterpret_cast<const int4*>(mask + base);
    float4 p;
    p.x = (m4.x == 0) ? -1.0e9f : 0.0f;
    p.y = (m4.y == 0) ? -1.0e9f : 0.0f;
    p.z = (m4.z == 0) ? -1.0e9f : 0.0f;
    p.w = (m4.w == 0) ? -1.0e9f : 0.0f;
    *reinterpret_cast<float4*>(Mf + base) = p;
    return;
  }
  const float* src;
  unsigned short* dst;
  float scale = 1.0f;
  if (z < 3) {
    src = (z == 0) ? q : (z == 1) ? k : v;
    dst = Ab + (size_t)z * BB * SS * DD;
  } else {
    if (blockIdx.x >= (DD * DD / 1024)) return;
    src = (z == 3) ? Wq : (z == 4) ? Wk : (z == 5) ? Wv : Wo;
    dst = Wb + (size_t)(z - 3) * DD * DD;
    if (z == 3) scale = 0.125f * 1.44269504088896f;
  }
  const size_t base = (size_t)blockIdx.x * 1024 + (size_t)threadIdx.x * 4;
  float4 val = *reinterpret_cast<const float4*>(src + base);
  val.x *= scale; val.y *= scale; val.z *= scale; val.w *= scale;
  uint2 p = pack4(val);
  *reinterpret_cast<uint2*>(dst + base) = p;
}

// ---------------- Q/K/V projections (pure bf16, xor-swizzled LDS) ----------------
__global__ __launch_bounds__(256) void proj128_kernel(
    const unsigned short* __restrict__ Ab, const unsigned short* __restrict__ Wb,
    unsigned short* __restrict__ Qb, unsigned short* __restrict__ Kb,
    unsigned short* __restrict__ Vt) {
  __shared__ unsigned short sA[128 * 64];
  __shared__ unsigned short sB[128 * 64];

  const int z = blockIdx.z;
  const unsigned short* A = Ab + (size_t)z * BB * SS * DD;
  const unsigned short* W = Wb + (size_t)z * DD * DD;
  unsigned short* Out = (z == 0) ? Qb : (z == 1) ? Kb : Vt;
  const int layout = (z == 2) ? 1 : 0;

  const int t = threadIdx.x;
  const int lane = t & 63, wave = t >> 6;
  const int quad = lane >> 4, l15 = lane & 15;
  const int wr = wave >> 1, wc = wave & 1;
  const int mBase = blockIdx.x * 128, nBase = blockIdx.y * 128;

  f32x4 acc[4][4] = {};

  for (int k0 = 0; k0 < DD; k0 += 64) {
    #pragma unroll
    for (int i = 0; i < 4; ++i) {
      const int g = wave * 4 + i;
      const int row = g * 8 + (lane >> 3);
      const int oct = (lane & 7) ^ (row & 7);
      gload_lds16(A + (size_t)(mBase + row) * DD + k0 + oct * 8, &sA[g * 512]);
      gload_lds16(W + (size_t)(nBase + row) * DD + k0 + oct * 8, &sB[g * 512]);
    }
    __syncthreads();

    #pragma unroll
    for (int kk = 0; kk < 2; ++kk) {
      bf16x8 af[4], bfr[4];
      #pragma unroll
      for (int i = 0; i < 4; ++i) {
        const int row = wr * 64 + i * 16 + l15;
        af[i] = ldsFrag(sA, (row * 8 + ((kk * 4 + quad) ^ (l15 & 7))) * 8);
      }
      #pragma unroll
      for (int j = 0; j < 4; ++j) {
        const int row = wc * 64 + j * 16 + l15;
        bfr[j] = ldsFrag(sB, (row * 8 + ((kk * 4 + quad) ^ (l15 & 7))) * 8);
      }
      #pragma unroll
      for (int i = 0; i < 4; ++i)
        #pragma unroll
        for (int j = 0; j < 4; ++j)
          acc[i][j] = MFMA16(af[i], bfr[j], acc[i][j]);
    }
    __syncthreads();
  }

  #pragma unroll
  for (int i = 0; i < 4; ++i) {
    #pragma unroll
    for (int j = 0; j < 4; ++j) {
      #pragma unroll
      for (int r = 0; r < 4; ++r) {
        int m = mBase + wr * 64 + i * 16 + quad * 4 + r;
        int n = nBase + wc * 64 + j * 16 + l15;
        int b = m >> 11, s = m & (SS - 1);
        int h = n >> 6, dh = n & (DHH - 1);
        size_t off;
        if (layout == 0)
          off = ((size_t)(b * HH + h) * SS + s) * DHH + dh;
        else
          off = ((size_t)(b * HH + h) * DHH + dh) * SS + s;
        Out[off] = f2bf(acc[i][j][r]);
      }
    }
  }
}

// ---------------- flash attention, S^T formulation ----------------
// 1024 blocks, one 64-row q-tile each. S^T = MFMA(K, Q); softmaxed S^T C-tile
// IS the B-frag of mfma 16x16x16 for O^T = V^T * P^T (zero-move transform).
// id -> (head-group via id&7) for XCD L2 locality; big q-tiles first.
__global__ __launch_bounds__(256, 4) void attn_kernel(
    const unsigned short* __restrict__ Qb, const unsigned short* __restrict__ Kb,
    const unsigned short* __restrict__ Vt, const float* __restrict__ Mf,
    unsigned short* __restrict__ Ob) {
  __shared__ __align__(16) char smem[32768];
  unsigned short* sK = (unsigned short*)smem;            // [key128][dh64] swizzled
  unsigned short* sV = (unsigned short*)(smem + 16384);  // [dh64][key128] swizzled
  unsigned short* sO = (unsigned short*)smem;            // overlay: [q64][dh64] stride 72

  const int t = threadIdx.x;
  const int lane = t & 63, wave = t >> 6;
  const int quad = lane >> 4, l15 = lane & 15;

  const int id = blockIdx.x;
  const int xcd = id & 7, rest = id >> 3;        // rest 0..127
  const int hd = xcd * 4 + (rest >> 5);          // head-index 0..31 (4 heads per XCD)
  const int qt = 31 - (rest & 31);               // big tiles dispatched first
  const int b = hd >> 4, h = hd & 15;
  const int qb = qt * 64;

  const size_t headOff = (size_t)hd * SS * DHH;
  const unsigned short* Qh = Qb + headOff;  // [S][64]
  const unsigned short* Kh = Kb + headOff;  // [S][64]
  const unsigned short* Vh = Vt + headOff;  // [64][S]
  const float* Mp = Mf + b * SS;

  // Q B-frags straight from global (no LDS round-trip)
  bf16x8 aq[2];
  {
    const unsigned short* qp = Qh + (size_t)(qb + wave * 16 + l15) * DHH + quad * 8;
    FragU f0, f1;
    f0.u = *reinterpret_cast<const uint4*>(qp);
    f1.u = *reinterpret_cast<const uint4*>(qp + 32);
    aq[0] = f0.b; aq[1] = f1.b;
  }

  float m_l = -1.0e30f, l_l = 0.0f;
  f32x4 oacc[4] = {};
  const int nc = (qt + 2) >> 1;
  const int qrow_abs = qb + wave * 16 + l15;

  for (int c = 0; c < nc; ++c) {
    const int c0 = c * 128;
    // stage K chunk [key][dh] swizzled
    #pragma unroll
    for (int i = 0; i < 4; ++i) {
      const int g = wave * 4 + i;
      const int row = g * 8 + (lane >> 3);
      const int oct = (lane & 7) ^ (row & 7);
      gload_lds16(Kh + (size_t)(c0 + row) * DHH + oct * 8, &sK[g * 512]);
    }
    // stage V^T chunk [dh][key] swizzled
    #pragma unroll
    for (int i = 0; i < 4; ++i) {
      const int g = wave * 4 + i;
      const int row = g * 4 + (lane >> 4);
      const int oct = (lane & 15) ^ (row & 15);
      gload_lds16(Vh + (size_t)row * SS + c0 + oct * 8, &sV[g * 512]);
    }
    __syncthreads();

    // S^T tiles: sacc[j] holds S^T[key=quad*4+r][qrow=l15] for key-tile j
    f32x4 sacc[8] = {};
    #pragma unroll
    for (int kk = 0; kk < 2; ++kk) {
      #pragma unroll
      for (int j = 0; j < 8; ++j) {
        const int row = j * 16 + l15;
        bf16x8 ak = ldsFrag(sK, (row * 8 + ((kk * 4 + quad) ^ (l15 & 7))) * 8);
        sacc[j] = MFMA16(ak, aq[kk], sacc[j]);
      }
    }

    // per-lane row max (all 32 values share qrow=l15); reduce across quads
    float rm = -1.0e30f;
    #pragma unroll
    for (int j = 0; j < 8; ++j)
      rm = fmaxf(rm, fmaxf(fmaxf(sacc[j][0], sacc[j][1]), fmaxf(sacc[j][2], sacc[j][3])));
    rm = fmaxf(rm, __shfl_xor(rm, 16));
    rm = fmaxf(rm, __shfl_xor(rm, 32));
    const float mnew = fmaxf(m_l, rm);
    const float alpha = EXP2(m_l - mnew);
    m_l = mnew;

    // p = exp2(s - m + pad); pack into B-frags (pk[j]) in-register
    const bool diag = (c == nc - 1);
    float rs = 0.0f;
    s16x4 pk[8];
    #pragma unroll
    for (int j = 0; j < 8; ++j) {
      float4 pf = *reinterpret_cast<const float4*>(Mp + c0 + j * 16 + quad * 4);
      float p0 = EXP2(sacc[j][0] - mnew + pf.x);
      float p1 = EXP2(sacc[j][1] - mnew + pf.y);
      float p2 = EXP2(sacc[j][2] - mnew + pf.z);
      float p3 = EXP2(sacc[j][3] - mnew + pf.w);
      if (diag) {
        const int key = c0 + j * 16 + quad * 4;
        p0 = (key + 0 > qrow_abs) ? 0.0f : p0;
        p1 = (key + 1 > qrow_abs) ? 0.0f : p1;
        p2 = (key + 2 > qrow_abs) ? 0.0f : p2;
        p3 = (key + 3 > qrow_abs) ? 0.0f : p3;
      }
      rs += (p0 + p1) + (p2 + p3);
      Frag4U fu;
      fu.u.x = __builtin_amdgcn_perm(__float_as_uint(p1) + 0x8000u,
                                     __float_as_uint(p0) + 0x8000u, 0x07060302u);
      fu.u.y = __builtin_amdgcn_perm(__float_as_uint(p3) + 0x8000u,
                                     __float_as_uint(p2) + 0x8000u, 0x07060302u);
      pk[j] = fu.s;
    }
    rs += __shfl_xor(rs, 16);
    rs += __shfl_xor(rs, 32);
    l_l = l_l * alpha + rs;

    #pragma unroll
    for (int jn = 0; jn < 4; ++jn)
      oacc[jn] *= alpha;

    // O^T += V^T_j * P^T_j  (K=16 MFMA; pk[j] is already the B operand)
    #pragma unroll
    for (int j = 0; j < 8; ++j) {
      #pragma unroll
      for (int jn = 0; jn < 4; ++jn) {
        const int row = jn * 16 + l15;
        const int unit = row * 16 + ((2 * j + (quad >> 1)) ^ l15);
        Frag4U av;
        av.u = *reinterpret_cast<const uint2*>(&sV[unit * 8 + (quad & 1) * 4]);
        oacc[jn] = MFMA16K16(av.s, pk[j], oacc[jn]);
      }
    }
    __syncthreads();
  }

  // epilogue: normalize, transpose O^T -> O via sO, coalesced store
  const float inv = 1.0f / l_l;
  #pragma unroll
  for (int jn = 0; jn < 4; ++jn) {
    uint2 w;
    w.x = (unsigned)f2bf(oacc[jn][0] * inv) | ((unsigned)f2bf(oacc[jn][1] * inv) << 16);
    w.y = (unsigned)f2bf(oacc[jn][2] * inv) | ((unsigned)f2bf(oacc[jn][3] * inv) << 16);
    *reinterpret_cast<uint2*>(&sO[(wave * 16 + l15) * 72 + jn * 16 + quad * 4]) = w;
  }
  __syncthreads();
  {
    const int row = t >> 2, seg = t & 3;
    uint4 u0 = *reinterpret_cast<const uint4*>(&sO[row * 72 + seg * 16]);
    uint4 u1 = *reinterpret_cast<const uint4*>(&sO[row * 72 + seg * 16 + 8]);
    unsigned short* dst = Ob + (size_t)(b * SS + qb + row) * DD + h * DHH + seg * 16;
    *reinterpret_cast<uint4*>(dst) = u0;
    *reinterpret_cast<uint4*>(dst + 8) = u1;
  }
}

// ---------------- output projection ----------------
__global__ __launch_bounds__(256) void outproj_kernel(
    const unsigned short* __restrict__ Ag, const unsigned short* __restrict__ Wb,
    float* __restrict__ Out) {
  __shared__ unsigned short sA[128 * 64];
  __shared__ unsigned short sB[128 * 64];

  const unsigned short* W = Wb + (size_t)3 * DD * DD;  // Wo
  const int t = threadIdx.x;
  const int lane = t & 63, wave = t >> 6;
  const int quad = lane >> 4, l15 = lane & 15;
  const int wr = wave >> 1, wc = wave & 1;
  const int mBase = blockIdx.x * 128, nBase = blockIdx.y * 128;

  f32x4 acc[4][4] = {};

  for (int k0 = 0; k0 < DD; k0 += 64) {
    #pragma unroll
    for (int i = 0; i < 4; ++i) {
      const int g = wave * 4 + i;
      const int row = g * 8 + (lane >> 3);
      const int oct = (lane & 7) ^ (row & 7);
      gload_lds16(Ag + (size_t)(mBase + row) * DD + k0 + oct * 8, &sA[g * 512]);
      gload_lds16(W + (size_t)(nBase + row) * DD + k0 + oct * 8, &sB[g * 512]);
    }
    __syncthreads();

    #pragma unroll
    for (int kk = 0; kk < 2; ++kk) {
      bf16x8 af[4], bfr[4];
      #pragma unroll
      for (int i = 0; i < 4; ++i) {
        const int row = wr * 64 + i * 16 + l15;
        af[i] = ldsFrag(sA, (row * 8 + ((kk * 4 + quad) ^ (l15 & 7))) * 8);
      }
      #pragma unroll
      for (int j = 0; j < 4; ++j) {
        const int row = wc * 64 + j * 16 + l15;
        bfr[j] = ldsFrag(sB, (row * 8 + ((kk * 4 + quad) ^ (l15 & 7))) * 8);
      }
      #pragma unroll
      for (int i = 0; i < 4; ++i)
        #pragma unroll
        for (int j = 0; j < 4; ++j)
          acc[i][j] = MFMA16(af[i], bfr[j], acc[i][j]);
    }
    __syncthreads();
  }

  #pragma unroll
  for (int i = 0; i < 4; ++i) {
    #pragma unroll
    for (int j = 0; j < 4; ++j) {
      #pragma unroll
      for (int r = 0; r < 4; ++r) {
        int m = mBase + wr * 64 + i * 16 + quad * 4 + r;
        int n = nBase + wc * 64 + j * 16 + l15;
        Out[(size_t)m * DD + n] = acc[i][j][r];
      }
    }
  }
}

extern "C" void kernel_launch(void* const* d_in, const int* in_sizes, int n_in,
                              void* d_out, int out_size, void* d_ws, size_t ws_size,
                              hipStream_t stream) {
  (void)in_sizes; (void)n_in; (void)out_size; (void)ws_size;
  const float* q  = (const float*)d_in[0];
  const float* k  = (const float*)d_in[1];
  const float* v  = (const float*)d_in[2];
  const int* mask = (const int*)d_in[3];
  const float* Wq = (const float*)d_in[4];
  const float* Wk = (const float*)d_in[5];
  const float* Wv = (const float*)d_in[6];
  const float* Wo = (const float*)d_in[7];
  float* out = (float*)d_out;

  const size_t AE = (size_t)BB * SS * DD;  // 4M elements per activation
  unsigned short* Ab = (unsigned short*)d_ws;       // 3 x AE bf16 (24 MB)
  unsigned short* Ob = Ab;                          // aliases Ab (dead after proj)
  unsigned short* Wb = Ab + 3 * AE;                 // 4 x DD*DD bf16 (8 MB)
  unsigned short* Qb = Wb + (size_t)4 * DD * DD;    // 8 MB each
  unsigned short* Kb = Qb + AE;
  unsigned short* Vt = Kb + AE;
  float* Mf = (float*)(Vt + AE);                    // BB*SS floats (16 KB)

  // 1. convert activations + weights (Wq pre-scaled by 0.125*log2e) + mask pad
  convert_kernel<<<dim3(AE / 1024, 8), 256, 0, stream>>>(
      q, k, v, Wq, Wk, Wv, Wo, mask, Ab, Wb, Mf);

  // 2. Q/K/V projections
  proj128_kernel<<<dim3(BB * SS / 128, DD / 128, 3), 256, 0, stream>>>(
      Ab, Wb, Qb, Kb, Vt);

  // 3. flash attention (S^T formulation, 1024 blocks, XCD-grouped)
  attn_kernel<<<dim3(32 * HH * BB), 256, 0, stream>>>(Qb, Kb, Vt, Mf, Ob);

  // 4. output projection
  outproj_kernel<<<dim3(BB * SS / 128, DD / 128), 256, 0, stream>>>(Ob, Wb, out);
}

// Round 6
// 241.880 us; speedup vs baseline: 1.0515x; 1.0515x over previous
//
#include <hip/hip_runtime.h>
#include <stdint.h>

// Problem constants
#define BB 2
#define SS 2048
#define DD 1024
#define HH 16
#define DHH 64

typedef __bf16 bf16_t;
typedef bf16_t bf16x8 __attribute__((ext_vector_type(8)));
typedef float f32x4 __attribute__((ext_vector_type(4)));
typedef short s16x4 __attribute__((ext_vector_type(4)));

union FragU { uint4 u; bf16x8 b; };
union Frag4U { uint2 u; s16x4 s; };

#if __has_builtin(__builtin_amdgcn_exp2f)
#define EXP2(x) __builtin_amdgcn_exp2f(x)
#else
#define EXP2(x) exp2f(x)
#endif

__device__ __forceinline__ unsigned short f2bf(float f) {
  union { float f; unsigned int u; } x; x.f = f;
  unsigned int u = x.u;
  return (unsigned short)((u + 0x7FFFu + ((u >> 16) & 1u)) >> 16);  // RNE
}

__device__ __forceinline__ uint2 pack4(float4 v) {
  uint2 r;
  r.x = (unsigned)f2bf(v.x) | ((unsigned)f2bf(v.y) << 16);
  r.y = (unsigned)f2bf(v.z) | ((unsigned)f2bf(v.w) << 16);
  return r;
}

__device__ __forceinline__ bf16x8 ldsFrag(const unsigned short* s, int idx) {
  FragU f;
  f.u = *reinterpret_cast<const uint4*>(s + idx);
  return f.b;
}

// async global -> LDS, 16 bytes per lane. LDS dest = wave-uniform base + lane*16.
__device__ __forceinline__ void gload_lds16(const unsigned short* g, unsigned short* s) {
  __builtin_amdgcn_global_load_lds(
      (const __attribute__((address_space(1))) unsigned int*)g,
      (__attribute__((address_space(3))) unsigned int*)s, 16, 0, 0);
}

#define MFMA16(a, b, c) __builtin_amdgcn_mfma_f32_16x16x32_bf16((a), (b), (c), 0, 0, 0)
#define MFMA16K16(a, b, c) __builtin_amdgcn_mfma_f32_16x16x16bf16_1k((a), (b), (c), 0, 0, 0)

// ---- fp32 -> bf16 convert: activations (z=0..2) + weights (z=3..6) + mask pad (z=7) ----
// Wq (z==3) pre-scaled by (1/8)*log2(e) (score scale + exp2-domain fold).
__global__ __launch_bounds__(256) void convert_kernel(
    const float* __restrict__ q, const float* __restrict__ k, const float* __restrict__ v,
    const float* __restrict__ Wq, const float* __restrict__ Wk,
    const float* __restrict__ Wv, const float* __restrict__ Wo,
    const int* __restrict__ mask,
    unsigned short* __restrict__ Ab, unsigned short* __restrict__ Wb,
    float* __restrict__ Mf) {
  const int z = blockIdx.y;
  if (z == 7) {  // mask -> additive pad floats (BB*SS = 4096 elements)
    if (blockIdx.x >= 4) return;
    const size_t base = (size_t)blockIdx.x * 1024 + (size_t)threadIdx.x * 4;
    int4 m4 = *reinterpret_cast<const int4*>(mask + base);
    float4 p;
    p.x = (m4.x == 0) ? -1.0e9f : 0.0f;
    p.y = (m4.y == 0) ? -1.0e9f : 0.0f;
    p.z = (m4.z == 0) ? -1.0e9f : 0.0f;
    p.w = (m4.w == 0) ? -1.0e9f : 0.0f;
    *reinterpret_cast<float4*>(Mf + base) = p;
    return;
  }
  const float* src;
  unsigned short* dst;
  float scale = 1.0f;
  if (z < 3) {
    src = (z == 0) ? q : (z == 1) ? k : v;
    dst = Ab + (size_t)z * BB * SS * DD;
  } else {
    if (blockIdx.x >= (DD * DD / 1024)) return;
    src = (z == 3) ? Wq : (z == 4) ? Wk : (z == 5) ? Wv : Wo;
    dst = Wb + (size_t)(z - 3) * DD * DD;
    if (z == 3) scale = 0.125f * 1.44269504088896f;
  }
  const size_t base = (size_t)blockIdx.x * 1024 + (size_t)threadIdx.x * 4;
  float4 val = *reinterpret_cast<const float4*>(src + base);
  val.x *= scale; val.y *= scale; val.z *= scale; val.w *= scale;
  uint2 p = pack4(val);
  *reinterpret_cast<uint2*>(dst + base) = p;
}

// ---------------- Q/K/V projections: 64x128 tile, double-buffered single-barrier K-loop ----
// z=0: Q -> [b][h][s][dh]; z=1: K -> same; z=2: V -> [b][h][dh][s]
__global__ __launch_bounds__(256, 3) void proj_kernel(
    const unsigned short* __restrict__ Ab, const unsigned short* __restrict__ Wb,
    unsigned short* __restrict__ Qb, unsigned short* __restrict__ Kb,
    unsigned short* __restrict__ Vt) {
  __shared__ unsigned short sA[2][64 * 64];
  __shared__ unsigned short sB[2][128 * 64];

  const int z = blockIdx.z;
  const unsigned short* A = Ab + (size_t)z * BB * SS * DD;
  const unsigned short* W = Wb + (size_t)z * DD * DD;
  unsigned short* Out = (z == 0) ? Qb : (z == 1) ? Kb : Vt;
  const int layout = (z == 2) ? 1 : 0;

  const int t = threadIdx.x;
  const int lane = t & 63, wave = t >> 6;
  const int quad = lane >> 4, l15 = lane & 15;
  const int wr = wave >> 1, wc = wave & 1;
  const int mBase = blockIdx.x * 64, nBase = blockIdx.y * 128;
  const int srow = lane >> 3, soct = lane & 7;

  f32x4 acc[2][4] = {};

  // initial stage: k0 = 0 -> buf 0
  #pragma unroll
  for (int i = 0; i < 2; ++i) {
    const int g = wave * 2 + i;
    const int row = g * 8 + srow;
    const int oct = soct ^ (row & 7);
    gload_lds16(A + (size_t)(mBase + row) * DD + oct * 8, &sA[0][g * 512]);
  }
  #pragma unroll
  for (int i = 0; i < 4; ++i) {
    const int g = wave * 4 + i;
    const int row = g * 8 + srow;
    const int oct = soct ^ (row & 7);
    gload_lds16(W + (size_t)(nBase + row) * DD + oct * 8, &sB[0][g * 512]);
  }

  for (int kt = 0; kt < DD / 64; ++kt) {
    __syncthreads();
    if (kt + 1 < DD / 64) {
      const int k1 = (kt + 1) * 64;
      const int nb = (kt + 1) & 1;
      #pragma unroll
      for (int i = 0; i < 2; ++i) {
        const int g = wave * 2 + i;
        const int row = g * 8 + srow;
        const int oct = soct ^ (row & 7);
        gload_lds16(A + (size_t)(mBase + row) * DD + k1 + oct * 8, &sA[nb][g * 512]);
      }
      #pragma unroll
      for (int i = 0; i < 4; ++i) {
        const int g = wave * 4 + i;
        const int row = g * 8 + srow;
        const int oct = soct ^ (row & 7);
        gload_lds16(W + (size_t)(nBase + row) * DD + k1 + oct * 8, &sB[nb][g * 512]);
      }
    }
    const int cb = kt & 1;
    #pragma unroll
    for (int kk = 0; kk < 2; ++kk) {
      bf16x8 af[2], bfr[4];
      #pragma unroll
      for (int i = 0; i < 2; ++i) {
        const int row = wr * 32 + i * 16 + l15;
        af[i] = ldsFrag(sA[cb], (row * 8 + ((kk * 4 + quad) ^ (l15 & 7))) * 8);
      }
      #pragma unroll
      for (int j = 0; j < 4; ++j) {
        const int row = wc * 64 + j * 16 + l15;
        bfr[j] = ldsFrag(sB[cb], (row * 8 + ((kk * 4 + quad) ^ (l15 & 7))) * 8);
      }
      #pragma unroll
      for (int i = 0; i < 2; ++i)
        #pragma unroll
        for (int j = 0; j < 4; ++j)
          acc[i][j] = MFMA16(af[i], bfr[j], acc[i][j]);
    }
  }

  // Epilogue: scatter bf16 to head layout
  #pragma unroll
  for (int i = 0; i < 2; ++i) {
    #pragma unroll
    for (int j = 0; j < 4; ++j) {
      #pragma unroll
      for (int r = 0; r < 4; ++r) {
        int m = mBase + wr * 32 + i * 16 + quad * 4 + r;
        int n = nBase + wc * 64 + j * 16 + l15;
        int b = m >> 11, s = m & (SS - 1);
        int h = n >> 6, dh = n & (DHH - 1);
        size_t off;
        if (layout == 0)
          off = ((size_t)(b * HH + h) * SS + s) * DHH + dh;
        else
          off = ((size_t)(b * HH + h) * DHH + dh) * SS + s;
        Out[off] = f2bf(acc[i][j][r]);
      }
    }
  }
}

// ---------------- flash attention: S^T form, 64-key chunks, double-buffered ----------------
// 1024 blocks (one 64-row q-tile each), XCD-grouped heads, big q-tiles first.
// Output head-blocked: Obh[b][h][s][dh] (dense 8KB per block -> full-line writes).
__global__ __launch_bounds__(256, 4) void attn_kernel(
    const unsigned short* __restrict__ Qb, const unsigned short* __restrict__ Kb,
    const unsigned short* __restrict__ Vt, const float* __restrict__ Mf,
    unsigned short* __restrict__ Obh) {
  __shared__ __align__(16) unsigned short sK[2][64 * 64];
  __shared__ __align__(16) unsigned short sV[2][64 * 64];
  unsigned short* sO = &sK[0][0];  // epilogue overlay (guarded by barrier)

  const int t = threadIdx.x;
  const int lane = t & 63, wave = t >> 6;
  const int quad = lane >> 4, l15 = lane & 15;

  const int id = blockIdx.x;
  const int xcd = id & 7, rest = id >> 3;    // rest 0..127
  const int hd = xcd * 4 + (rest >> 5);      // 4 heads per XCD group
  const int qt = 31 - (rest & 31);           // big q-tiles first
  const int b = hd >> 4;
  const int qb = qt * 64;

  const size_t headOff = (size_t)hd * SS * DHH;
  const unsigned short* Qh = Qb + headOff;  // [S][64]
  const unsigned short* Kh = Kb + headOff;  // [S][64]
  const unsigned short* Vh = Vt + headOff;  // [64][S]
  const float* Mp = Mf + b * SS;

  // Q B-frags straight from global
  bf16x8 aq[2];
  {
    const unsigned short* qp = Qh + (size_t)(qb + wave * 16 + l15) * DHH + quad * 8;
    FragU f0, f1;
    f0.u = *reinterpret_cast<const uint4*>(qp);
    f1.u = *reinterpret_cast<const uint4*>(qp + 32);
    aq[0] = f0.b; aq[1] = f1.b;
  }

  const int srow = lane >> 3, soct = lane & 7;

  // initial stage: chunk 0 -> buf 0
  #pragma unroll
  for (int i = 0; i < 2; ++i) {
    const int g = wave * 2 + i;
    const int row = g * 8 + srow;
    const int oct = soct ^ (row & 7);
    gload_lds16(Kh + (size_t)row * DHH + oct * 8, &sK[0][g * 512]);
    gload_lds16(Vh + (size_t)row * SS + oct * 8, &sV[0][g * 512]);
  }

  float m_l = -1.0e30f, l_l = 0.0f;
  f32x4 oacc[4] = {};
  const int qrow_abs = qb + wave * 16 + l15;

  for (int c = 0; c <= qt; ++c) {
    __syncthreads();  // buf[c&1] ready; buf[(c+1)&1] readers (chunk c-1) done
    if (c < qt) {
      const int c1 = (c + 1) * 64;
      const int nb = (c + 1) & 1;
      #pragma unroll
      for (int i = 0; i < 2; ++i) {
        const int g = wave * 2 + i;
        const int row = g * 8 + srow;
        const int oct = soct ^ (row & 7);
        gload_lds16(Kh + (size_t)(c1 + row) * DHH + oct * 8, &sK[nb][g * 512]);
        gload_lds16(Vh + (size_t)row * SS + c1 + oct * 8, &sV[nb][g * 512]);
      }
    }
    const int cb = c & 1;
    const int c0 = c * 64;

    // S^T tiles: sacc[j] = S^T[key=quad*4+r][q=l15], key-tile j
    f32x4 sacc[4] = {};
    #pragma unroll
    for (int kk = 0; kk < 2; ++kk) {
      #pragma unroll
      for (int j = 0; j < 4; ++j) {
        const int row = j * 16 + l15;
        bf16x8 ak = ldsFrag(sK[cb], (row * 8 + ((kk * 4 + quad) ^ (l15 & 7))) * 8);
        sacc[j] = MFMA16(ak, aq[kk], sacc[j]);
      }
    }

    // row max across quads (all values in a lane share q-row l15)
    float rm = -1.0e30f;
    #pragma unroll
    for (int j = 0; j < 4; ++j)
      rm = fmaxf(rm, fmaxf(fmaxf(sacc[j][0], sacc[j][1]), fmaxf(sacc[j][2], sacc[j][3])));
    rm = fmaxf(rm, __shfl_xor(rm, 16));
    rm = fmaxf(rm, __shfl_xor(rm, 32));
    const float mnew = fmaxf(m_l, rm);
    const float alpha = EXP2(m_l - mnew);
    m_l = mnew;

    // p = exp2(s - m + pad); pack B-frags in-register
    const bool diag = (c == qt);
    float rs = 0.0f;
    s16x4 pk[4];
    #pragma unroll
    for (int j = 0; j < 4; ++j) {
      float4 pf = *reinterpret_cast<const float4*>(Mp + c0 + j * 16 + quad * 4);
      float p0 = EXP2(sacc[j][0] - mnew + pf.x);
      float p1 = EXP2(sacc[j][1] - mnew + pf.y);
      float p2 = EXP2(sacc[j][2] - mnew + pf.z);
      float p3 = EXP2(sacc[j][3] - mnew + pf.w);
      if (diag) {
        const int key = c0 + j * 16 + quad * 4;
        p0 = (key + 0 > qrow_abs) ? 0.0f : p0;
        p1 = (key + 1 > qrow_abs) ? 0.0f : p1;
        p2 = (key + 2 > qrow_abs) ? 0.0f : p2;
        p3 = (key + 3 > qrow_abs) ? 0.0f : p3;
      }
      rs += (p0 + p1) + (p2 + p3);
      Frag4U fu;
      fu.u.x = __builtin_amdgcn_perm(__float_as_uint(p1) + 0x8000u,
                                     __float_as_uint(p0) + 0x8000u, 0x07060302u);
      fu.u.y = __builtin_amdgcn_perm(__float_as_uint(p3) + 0x8000u,
                                     __float_as_uint(p2) + 0x8000u, 0x07060302u);
      pk[j] = fu.s;
    }
    rs += __shfl_xor(rs, 16);
    rs += __shfl_xor(rs, 32);
    l_l = l_l * alpha + rs;

    #pragma unroll
    for (int jn = 0; jn < 4; ++jn)
      oacc[jn] *= alpha;

    // O^T += V^T_j * P^T_j (K=16 MFMA; pk[j] already the B operand)
    #pragma unroll
    for (int j = 0; j < 4; ++j) {
      #pragma unroll
      for (int jn = 0; jn < 4; ++jn) {
        const int row = jn * 16 + l15;
        const int oct = (2 * j + (quad >> 1)) ^ (l15 & 7);
        Frag4U av;
        av.u = *reinterpret_cast<const uint2*>(&sV[cb][(row * 8 + oct) * 8 + (quad & 1) * 4]);
        oacc[jn] = MFMA16K16(av.s, pk[j], oacc[jn]);
      }
    }
  }

  // epilogue: normalize, transpose O^T -> O via sO, dense head-blocked store
  __syncthreads();
  const float inv = 1.0f / l_l;
  #pragma unroll
  for (int jn = 0; jn < 4; ++jn) {
    uint2 w;
    w.x = (unsigned)f2bf(oacc[jn][0] * inv) | ((unsigned)f2bf(oacc[jn][1] * inv) << 16);
    w.y = (unsigned)f2bf(oacc[jn][2] * inv) | ((unsigned)f2bf(oacc[jn][3] * inv) << 16);
    *reinterpret_cast<uint2*>(&sO[(wave * 16 + l15) * 72 + jn * 16 + quad * 4]) = w;
  }
  __syncthreads();
  {
    const int row = t >> 2, seg = t & 3;
    uint4 u0 = *reinterpret_cast<const uint4*>(&sO[row * 72 + seg * 16]);
    uint4 u1 = *reinterpret_cast<const uint4*>(&sO[row * 72 + seg * 16 + 8]);
    unsigned short* dst = Obh + headOff + (size_t)(qb + row) * DHH + seg * 16;
    *reinterpret_cast<uint4*>(dst) = u0;
    *reinterpret_cast<uint4*>(dst + 8) = u1;
  }
}

// ---------------- output projection: 64x128 tile, dbuf; A from head-blocked Obh ----------
// K-tile kt (BK=64) == head kt exactly (DHH=64, DD/64=16=HH).
__global__ __launch_bounds__(256, 3) void outproj_kernel(
    const unsigned short* __restrict__ Obh, const unsigned short* __restrict__ Wb,
    float* __restrict__ Out) {
  __shared__ unsigned short sA[2][64 * 64];
  __shared__ unsigned short sB[2][128 * 64];

  const unsigned short* W = Wb + (size_t)3 * DD * DD;  // Wo
  const int t = threadIdx.x;
  const int lane = t & 63, wave = t >> 6;
  const int quad = lane >> 4, l15 = lane & 15;
  const int wr = wave >> 1, wc = wave & 1;
  const int mBase = blockIdx.x * 64, nBase = blockIdx.y * 128;
  const int srow = lane >> 3, soct = lane & 7;

  const int bidx = mBase >> 11;
  const int sloc = mBase & (SS - 1);
  const unsigned short* Abase = Obh + (size_t)bidx * HH * SS * DHH;

  f32x4 acc[2][4] = {};

  #pragma unroll
  for (int i = 0; i < 2; ++i) {
    const int g = wave * 2 + i;
    const int row = g * 8 + srow;
    const int oct = soct ^ (row & 7);
    gload_lds16(Abase + ((size_t)0 * SS + sloc + row) * DHH + oct * 8, &sA[0][g * 512]);
  }
  #pragma unroll
  for (int i = 0; i < 4; ++i) {
    const int g = wave * 4 + i;
    const int row = g * 8 + srow;
    const int oct = soct ^ (row & 7);
    gload_lds16(W + (size_t)(nBase + row) * DD + oct * 8, &sB[0][g * 512]);
  }

  for (int kt = 0; kt < HH; ++kt) {
    __syncthreads();
    if (kt + 1 < HH) {
      const int nb = (kt + 1) & 1;
      #pragma unroll
      for (int i = 0; i < 2; ++i) {
        const int g = wave * 2 + i;
        const int row = g * 8 + srow;
        const int oct = soct ^ (row & 7);
        gload_lds16(Abase + ((size_t)(kt + 1) * SS + sloc + row) * DHH + oct * 8,
                    &sA[nb][g * 512]);
      }
      #pragma unroll
      for (int i = 0; i < 4; ++i) {
        const int g = wave * 4 + i;
        const int row = g * 8 + srow;
        const int oct = soct ^ (row & 7);
        gload_lds16(W + (size_t)(nBase + row) * DD + (kt + 1) * 64 + oct * 8,
                    &sB[nb][g * 512]);
      }
    }
    const int cb = kt & 1;
    #pragma unroll
    for (int kk = 0; kk < 2; ++kk) {
      bf16x8 af[2], bfr[4];
      #pragma unroll
      for (int i = 0; i < 2; ++i) {
        const int row = wr * 32 + i * 16 + l15;
        af[i] = ldsFrag(sA[cb], (row * 8 + ((kk * 4 + quad) ^ (l15 & 7))) * 8);
      }
      #pragma unroll
      for (int j = 0; j < 4; ++j) {
        const int row = wc * 64 + j * 16 + l15;
        bfr[j] = ldsFrag(sB[cb], (row * 8 + ((kk * 4 + quad) ^ (l15 & 7))) * 8);
      }
      #pragma unroll
      for (int i = 0; i < 2; ++i)
        #pragma unroll
        for (int j = 0; j < 4; ++j)
          acc[i][j] = MFMA16(af[i], bfr[j], acc[i][j]);
    }
  }

  #pragma unroll
  for (int i = 0; i < 2; ++i) {
    #pragma unroll
    for (int j = 0; j < 4; ++j) {
      #pragma unroll
      for (int r = 0; r < 4; ++r) {
        int m = mBase + wr * 32 + i * 16 + quad * 4 + r;
        int n = nBase + wc * 64 + j * 16 + l15;
        Out[(size_t)m * DD + n] = acc[i][j][r];
      }
    }
  }
}

extern "C" void kernel_launch(void* const* d_in, const int* in_sizes, int n_in,
                              void* d_out, int out_size, void* d_ws, size_t ws_size,
                              hipStream_t stream) {
  (void)in_sizes; (void)n_in; (void)out_size; (void)ws_size;
  const float* q  = (const float*)d_in[0];
  const float* k  = (const float*)d_in[1];
  const float* v  = (const float*)d_in[2];
  const int* mask = (const int*)d_in[3];
  const float* Wq = (const float*)d_in[4];
  const float* Wk = (const float*)d_in[5];
  const float* Wv = (const float*)d_in[6];
  const float* Wo = (const float*)d_in[7];
  float* out = (float*)d_out;

  const size_t AE = (size_t)BB * SS * DD;  // 4M elements per activation
  unsigned short* Ab  = (unsigned short*)d_ws;      // 3 x AE bf16 (24 MB)
  unsigned short* Obh = Ab;                         // aliases Ab (dead after proj)
  unsigned short* Wb  = Ab + 3 * AE;                // 4 x DD*DD bf16 (8 MB)
  unsigned short* Qb  = Wb + (size_t)4 * DD * DD;   // 8 MB each
  unsigned short* Kb  = Qb + AE;
  unsigned short* Vt  = Kb + AE;
  float* Mf = (float*)(Vt + AE);                    // BB*SS floats (16 KB)

  // 1. convert activations + weights (Wq pre-scaled by 0.125*log2e) + mask pad
  convert_kernel<<<dim3(AE / 1024, 8), 256, 0, stream>>>(
      q, k, v, Wq, Wk, Wv, Wo, mask, Ab, Wb, Mf);

  // 2. Q/K/V projections (64x128 tiles, dbuf)
  proj_kernel<<<dim3(BB * SS / 64, DD / 128, 3), 256, 0, stream>>>(
      Ab, Wb, Qb, Kb, Vt);

  // 3. flash attention (S^T form, 64-key dbuf chunks, head-blocked output)
  attn_kernel<<<dim3(32 * HH * BB), 256, 0, stream>>>(Qb, Kb, Vt, Mf, Obh);

  // 4. output projection (64x128 tiles, dbuf)
  outproj_kernel<<<dim3(BB * SS / 64, DD / 128), 256, 0, stream>>>(Obh, Wb, out);
}

// Round 7
// 233.086 us; speedup vs baseline: 1.0911x; 1.0377x over previous
//
#include <hip/hip_runtime.h>
#include <stdint.h>

// Problem constants
#define BB 2
#define SS 2048
#define DD 1024
#define HH 16
#define DHH 64

typedef __bf16 bf16_t;
typedef bf16_t bf16x8 __attribute__((ext_vector_type(8)));
typedef float f32x4 __attribute__((ext_vector_type(4)));
typedef short s16x4 __attribute__((ext_vector_type(4)));

union FragU { uint4 u; bf16x8 b; };
union Frag4U { uint2 u; s16x4 s; };

#if __has_builtin(__builtin_amdgcn_exp2f)
#define EXP2(x) __builtin_amdgcn_exp2f(x)
#else
#define EXP2(x) exp2f(x)
#endif

__device__ __forceinline__ unsigned short f2bf(float f) {
  union { float f; unsigned int u; } x; x.f = f;
  unsigned int u = x.u;
  return (unsigned short)((u + 0x7FFFu + ((u >> 16) & 1u)) >> 16);  // RNE
}

__device__ __forceinline__ uint2 pack4(float4 v) {
  uint2 r;
  r.x = (unsigned)f2bf(v.x) | ((unsigned)f2bf(v.y) << 16);
  r.y = (unsigned)f2bf(v.z) | ((unsigned)f2bf(v.w) << 16);
  return r;
}

__device__ __forceinline__ bf16x8 ldsFrag(const unsigned short* s, int idx) {
  FragU f;
  f.u = *reinterpret_cast<const uint4*>(s + idx);
  return f.b;
}

// async global -> LDS, 16 bytes per lane. LDS dest = wave-uniform base + lane*16.
__device__ __forceinline__ void gload_lds16(const unsigned short* g, unsigned short* s) {
  __builtin_amdgcn_global_load_lds(
      (const __attribute__((address_space(1))) unsigned int*)g,
      (__attribute__((address_space(3))) unsigned int*)s, 16, 0, 0);
}

#define MFMA16(a, b, c) __builtin_amdgcn_mfma_f32_16x16x32_bf16((a), (b), (c), 0, 0, 0)
#define MFMA16K16(a, b, c) __builtin_amdgcn_mfma_f32_16x16x16bf16_1k((a), (b), (c), 0, 0, 0)

// ---- fp32 -> bf16 convert: activations (z=0..2) + weights (z=3..6) + mask pad (z=7) ----
// Wq (z==3) pre-scaled by (1/8)*log2(e) (score scale + exp2-domain fold).
__global__ __launch_bounds__(256) void convert_kernel(
    const float* __restrict__ q, const float* __restrict__ k, const float* __restrict__ v,
    const float* __restrict__ Wq, const float* __restrict__ Wk,
    const float* __restrict__ Wv, const float* __restrict__ Wo,
    const int* __restrict__ mask,
    unsigned short* __restrict__ Ab, unsigned short* __restrict__ Wb,
    float* __restrict__ Mf) {
  const int z = blockIdx.y;
  if (z == 7) {  // mask -> additive pad floats (BB*SS = 4096 elements)
    if (blockIdx.x >= 4) return;
    const size_t base = (size_t)blockIdx.x * 1024 + (size_t)threadIdx.x * 4;
    int4 m4 = *reinterpret_cast<const int4*>(mask + base);
    float4 p;
    p.x = (m4.x == 0) ? -1.0e9f : 0.0f;
    p.y = (m4.y == 0) ? -1.0e9f : 0.0f;
    p.z = (m4.z == 0) ? -1.0e9f : 0.0f;
    p.w = (m4.w == 0) ? -1.0e9f : 0.0f;
    *reinterpret_cast<float4*>(Mf + base) = p;
    return;
  }
  const float* src;
  unsigned short* dst;
  float scale = 1.0f;
  if (z < 3) {
    src = (z == 0) ? q : (z == 1) ? k : v;
    dst = Ab + (size_t)z * BB * SS * DD;
  } else {
    if (blockIdx.x >= (DD * DD / 1024)) return;
    src = (z == 3) ? Wq : (z == 4) ? Wk : (z == 5) ? Wv : Wo;
    dst = Wb + (size_t)(z - 3) * DD * DD;
    if (z == 3) scale = 0.125f * 1.44269504088896f;
  }
  const size_t base = (size_t)blockIdx.x * 1024 + (size_t)threadIdx.x * 4;
  float4 val = *reinterpret_cast<const float4*>(src + base);
  val.x *= scale; val.y *= scale; val.z *= scale; val.w *= scale;
  uint2 p = pack4(val);
  *reinterpret_cast<uint2*>(dst + base) = p;
}

// ---------------- Q/K/V projections (128x128 tile, single-buf, swizzled LDS) ----------------
// z=0: Q -> [b][h][s][dh]; z=1: K -> same; z=2: V -> [b][h][dh][s]
__global__ __launch_bounds__(256) void proj128_kernel(
    const unsigned short* __restrict__ Ab, const unsigned short* __restrict__ Wb,
    unsigned short* __restrict__ Qb, unsigned short* __restrict__ Kb,
    unsigned short* __restrict__ Vt) {
  __shared__ unsigned short sA[128 * 64];
  __shared__ unsigned short sB[128 * 64];

  const int z = blockIdx.z;
  const unsigned short* A = Ab + (size_t)z * BB * SS * DD;
  const unsigned short* W = Wb + (size_t)z * DD * DD;
  unsigned short* Out = (z == 0) ? Qb : (z == 1) ? Kb : Vt;
  const int layout = (z == 2) ? 1 : 0;

  const int t = threadIdx.x;
  const int lane = t & 63, wave = t >> 6;
  const int quad = lane >> 4, l15 = lane & 15;
  const int wr = wave >> 1, wc = wave & 1;
  const int mBase = blockIdx.x * 128, nBase = blockIdx.y * 128;

  f32x4 acc[4][4] = {};

  for (int k0 = 0; k0 < DD; k0 += 64) {
    #pragma unroll
    for (int i = 0; i < 4; ++i) {
      const int g = wave * 4 + i;
      const int row = g * 8 + (lane >> 3);
      const int oct = (lane & 7) ^ (row & 7);
      gload_lds16(A + (size_t)(mBase + row) * DD + k0 + oct * 8, &sA[g * 512]);
      gload_lds16(W + (size_t)(nBase + row) * DD + k0 + oct * 8, &sB[g * 512]);
    }
    __syncthreads();

    #pragma unroll
    for (int kk = 0; kk < 2; ++kk) {
      bf16x8 af[4], bfr[4];
      #pragma unroll
      for (int i = 0; i < 4; ++i) {
        const int row = wr * 64 + i * 16 + l15;
        af[i] = ldsFrag(sA, (row * 8 + ((kk * 4 + quad) ^ (l15 & 7))) * 8);
      }
      #pragma unroll
      for (int j = 0; j < 4; ++j) {
        const int row = wc * 64 + j * 16 + l15;
        bfr[j] = ldsFrag(sB, (row * 8 + ((kk * 4 + quad) ^ (l15 & 7))) * 8);
      }
      #pragma unroll
      for (int i = 0; i < 4; ++i)
        #pragma unroll
        for (int j = 0; j < 4; ++j)
          acc[i][j] = MFMA16(af[i], bfr[j], acc[i][j]);
    }
    __syncthreads();
  }

  // Epilogue: scatter bf16 to head layout
  #pragma unroll
  for (int i = 0; i < 4; ++i) {
    #pragma unroll
    for (int j = 0; j < 4; ++j) {
      #pragma unroll
      for (int r = 0; r < 4; ++r) {
        int m = mBase + wr * 64 + i * 16 + quad * 4 + r;
        int n = nBase + wc * 64 + j * 16 + l15;
        int b = m >> 11, s = m & (SS - 1);
        int h = n >> 6, dh = n & (DHH - 1);
        size_t off;
        if (layout == 0)
          off = ((size_t)(b * HH + h) * SS + s) * DHH + dh;
        else
          off = ((size_t)(b * HH + h) * DHH + dh) * SS + s;
        Out[off] = f2bf(acc[i][j][r]);
      }
    }
  }
}

// ---------------- flash attention: S^T form, 64-key dbuf chunks, balanced mapping ------------
// 1024 blocks. CU-co-resident blocks (ids spaced 256) get qt sets {q,31-q,q,31-q}
// -> exactly 66 chunks per CU. XCD-grouped heads (4 heads per XCD group).
// Output head-blocked: Obh[b][h][s][dh] (dense 8KB per block).
__global__ __launch_bounds__(256, 4) void attn_kernel(
    const unsigned short* __restrict__ Qb, const unsigned short* __restrict__ Kb,
    const unsigned short* __restrict__ Vt, const float* __restrict__ Mf,
    unsigned short* __restrict__ Obh) {
  __shared__ __align__(16) unsigned short sK[2][64 * 64];
  __shared__ __align__(16) unsigned short sV[2][64 * 64];
  unsigned short* sO = &sK[0][0];  // epilogue overlay (guarded by barrier)

  const int t = threadIdx.x;
  const int lane = t & 63, wave = t >> 6;
  const int quad = lane >> 4, l15 = lane & 15;

  const int id = blockIdx.x;
  const int xcd = id & 7, rest = id >> 3;    // rest 0..127
  const int hg = rest >> 5;                  // head-in-group 0..3
  const int hd = xcd * 4 + hg;               // head-index 0..31
  const int r5 = rest & 31;
  const int qt = (hg & 1) ? (31 - r5) : r5;  // balanced across co-resident blocks
  const int b = hd >> 4;
  const int qb = qt * 64;

  const size_t headOff = (size_t)hd * SS * DHH;
  const unsigned short* Qh = Qb + headOff;  // [S][64]
  const unsigned short* Kh = Kb + headOff;  // [S][64]
  const unsigned short* Vh = Vt + headOff;  // [64][S]
  const float* Mp = Mf + b * SS;

  // Q B-frags straight from global
  bf16x8 aq[2];
  {
    const unsigned short* qp = Qh + (size_t)(qb + wave * 16 + l15) * DHH + quad * 8;
    FragU f0, f1;
    f0.u = *reinterpret_cast<const uint4*>(qp);
    f1.u = *reinterpret_cast<const uint4*>(qp + 32);
    aq[0] = f0.b; aq[1] = f1.b;
  }

  const int srow = lane >> 3, soct = lane & 7;

  // initial stage: chunk 0 -> buf 0
  #pragma unroll
  for (int i = 0; i < 2; ++i) {
    const int g = wave * 2 + i;
    const int row = g * 8 + srow;
    const int oct = soct ^ (row & 7);
    gload_lds16(Kh + (size_t)row * DHH + oct * 8, &sK[0][g * 512]);
    gload_lds16(Vh + (size_t)row * SS + oct * 8, &sV[0][g * 512]);
  }

  float m_l = -1.0e30f, l_l = 0.0f;
  f32x4 oacc[4] = {};
  const int qrow_abs = qb + wave * 16 + l15;

  for (int c = 0; c <= qt; ++c) {
    __syncthreads();  // buf[c&1] ready; buf[(c+1)&1] readers (chunk c-1) done
    if (c < qt) {
      const int c1 = (c + 1) * 64;
      const int nb = (c + 1) & 1;
      #pragma unroll
      for (int i = 0; i < 2; ++i) {
        const int g = wave * 2 + i;
        const int row = g * 8 + srow;
        const int oct = soct ^ (row & 7);
        gload_lds16(Kh + (size_t)(c1 + row) * DHH + oct * 8, &sK[nb][g * 512]);
        gload_lds16(Vh + (size_t)row * SS + c1 + oct * 8, &sV[nb][g * 512]);
      }
    }
    const int cb = c & 1;
    const int c0 = c * 64;

    // S^T tiles: sacc[j] = S^T[key=quad*4+r][q=l15], key-tile j
    f32x4 sacc[4] = {};
    #pragma unroll
    for (int kk = 0; kk < 2; ++kk) {
      #pragma unroll
      for (int j = 0; j < 4; ++j) {
        const int row = j * 16 + l15;
        bf16x8 ak = ldsFrag(sK[cb], (row * 8 + ((kk * 4 + quad) ^ (l15 & 7))) * 8);
        sacc[j] = MFMA16(ak, aq[kk], sacc[j]);
      }
    }

    // row max across quads (all values in a lane share q-row l15)
    float rm = -1.0e30f;
    #pragma unroll
    for (int j = 0; j < 4; ++j)
      rm = fmaxf(rm, fmaxf(fmaxf(sacc[j][0], sacc[j][1]), fmaxf(sacc[j][2], sacc[j][3])));
    rm = fmaxf(rm, __shfl_xor(rm, 16));
    rm = fmaxf(rm, __shfl_xor(rm, 32));
    const float mnew = fmaxf(m_l, rm);
    const float alpha = EXP2(m_l - mnew);
    m_l = mnew;

    // p = exp2(s - m + pad); pack B-frags in-register
    const bool diag = (c == qt);
    float rs = 0.0f;
    s16x4 pk[4];
    #pragma unroll
    for (int j = 0; j < 4; ++j) {
      float4 pf = *reinterpret_cast<const float4*>(Mp + c0 + j * 16 + quad * 4);
      float p0 = EXP2(sacc[j][0] - mnew + pf.x);
      float p1 = EXP2(sacc[j][1] - mnew + pf.y);
      float p2 = EXP2(sacc[j][2] - mnew + pf.z);
      float p3 = EXP2(sacc[j][3] - mnew + pf.w);
      if (diag) {
        const int key = c0 + j * 16 + quad * 4;
        p0 = (key + 0 > qrow_abs) ? 0.0f : p0;
        p1 = (key + 1 > qrow_abs) ? 0.0f : p1;
        p2 = (key + 2 > qrow_abs) ? 0.0f : p2;
        p3 = (key + 3 > qrow_abs) ? 0.0f : p3;
      }
      rs += (p0 + p1) + (p2 + p3);
      Frag4U fu;
      fu.u.x = __builtin_amdgcn_perm(__float_as_uint(p1) + 0x8000u,
                                     __float_as_uint(p0) + 0x8000u, 0x07060302u);
      fu.u.y = __builtin_amdgcn_perm(__float_as_uint(p3) + 0x8000u,
                                     __float_as_uint(p2) + 0x8000u, 0x07060302u);
      pk[j] = fu.s;
    }
    rs += __shfl_xor(rs, 16);
    rs += __shfl_xor(rs, 32);
    l_l = l_l * alpha + rs;

    #pragma unroll
    for (int jn = 0; jn < 4; ++jn)
      oacc[jn] *= alpha;

    // O^T += V^T_j * P^T_j (K=16 MFMA; pk[j] already the B operand)
    #pragma unroll
    for (int j = 0; j < 4; ++j) {
      #pragma unroll
      for (int jn = 0; jn < 4; ++jn) {
        const int row = jn * 16 + l15;
        const int oct = (2 * j + (quad >> 1)) ^ (l15 & 7);
        Frag4U av;
        av.u = *reinterpret_cast<const uint2*>(&sV[cb][(row * 8 + oct) * 8 + (quad & 1) * 4]);
        oacc[jn] = MFMA16K16(av.s, pk[j], oacc[jn]);
      }
    }
  }

  // epilogue: normalize, transpose O^T -> O via sO, dense head-blocked store
  __syncthreads();
  const float inv = 1.0f / l_l;
  #pragma unroll
  for (int jn = 0; jn < 4; ++jn) {
    uint2 w;
    w.x = (unsigned)f2bf(oacc[jn][0] * inv) | ((unsigned)f2bf(oacc[jn][1] * inv) << 16);
    w.y = (unsigned)f2bf(oacc[jn][2] * inv) | ((unsigned)f2bf(oacc[jn][3] * inv) << 16);
    *reinterpret_cast<uint2*>(&sO[(wave * 16 + l15) * 72 + jn * 16 + quad * 4]) = w;
  }
  __syncthreads();
  {
    const int row = t >> 2, seg = t & 3;
    uint4 u0 = *reinterpret_cast<const uint4*>(&sO[row * 72 + seg * 16]);
    uint4 u1 = *reinterpret_cast<const uint4*>(&sO[row * 72 + seg * 16 + 8]);
    unsigned short* dst = Obh + headOff + (size_t)(qb + row) * DHH + seg * 16;
    *reinterpret_cast<uint4*>(dst) = u0;
    *reinterpret_cast<uint4*>(dst + 8) = u1;
  }
}

// ---------------- output projection: 128x128 tile, single-buf; A head-blocked ----------------
// K-tile kt (BK=64) == head kt (DHH=64, DD/64=16=HH).
__global__ __launch_bounds__(256) void outproj_kernel(
    const unsigned short* __restrict__ Obh, const unsigned short* __restrict__ Wb,
    float* __restrict__ Out) {
  __shared__ unsigned short sA[128 * 64];
  __shared__ unsigned short sB[128 * 64];

  const unsigned short* W = Wb + (size_t)3 * DD * DD;  // Wo
  const int t = threadIdx.x;
  const int lane = t & 63, wave = t >> 6;
  const int quad = lane >> 4, l15 = lane & 15;
  const int wr = wave >> 1, wc = wave & 1;
  const int mBase = blockIdx.x * 128, nBase = blockIdx.y * 128;

  const int bidx = mBase >> 11;
  const int sloc = mBase & (SS - 1);
  const unsigned short* Abase = Obh + (size_t)bidx * HH * SS * DHH;

  f32x4 acc[4][4] = {};

  for (int kt = 0; kt < HH; ++kt) {
    #pragma unroll
    for (int i = 0; i < 4; ++i) {
      const int g = wave * 4 + i;
      const int row = g * 8 + (lane >> 3);
      const int oct = (lane & 7) ^ (row & 7);
      gload_lds16(Abase + ((size_t)kt * SS + sloc + row) * DHH + oct * 8, &sA[g * 512]);
      gload_lds16(W + (size_t)(nBase + row) * DD + kt * 64 + oct * 8, &sB[g * 512]);
    }
    __syncthreads();

    #pragma unroll
    for (int kk = 0; kk < 2; ++kk) {
      bf16x8 af[4], bfr[4];
      #pragma unroll
      for (int i = 0; i < 4; ++i) {
        const int row = wr * 64 + i * 16 + l15;
        af[i] = ldsFrag(sA, (row * 8 + ((kk * 4 + quad) ^ (l15 & 7))) * 8);
      }
      #pragma unroll
      for (int j = 0; j < 4; ++j) {
        const int row = wc * 64 + j * 16 + l15;
        bfr[j] = ldsFrag(sB, (row * 8 + ((kk * 4 + quad) ^ (l15 & 7))) * 8);
      }
      #pragma unroll
      for (int i = 0; i < 4; ++i)
        #pragma unroll
        for (int j = 0; j < 4; ++j)
          acc[i][j] = MFMA16(af[i], bfr[j], acc[i][j]);
    }
    __syncthreads();
  }

  #pragma unroll
  for (int i = 0; i < 4; ++i) {
    #pragma unroll
    for (int j = 0; j < 4; ++j) {
      #pragma unroll
      for (int r = 0; r < 4; ++r) {
        int m = mBase + wr * 64 + i * 16 + quad * 4 + r;
        int n = nBase + wc * 64 + j * 16 + l15;
        Out[(size_t)m * DD + n] = acc[i][j][r];
      }
    }
  }
}

extern "C" void kernel_launch(void* const* d_in, const int* in_sizes, int n_in,
                              void* d_out, int out_size, void* d_ws, size_t ws_size,
                              hipStream_t stream) {
  (void)in_sizes; (void)n_in; (void)out_size; (void)ws_size;
  const float* q  = (const float*)d_in[0];
  const float* k  = (const float*)d_in[1];
  const float* v  = (const float*)d_in[2];
  const int* mask = (const int*)d_in[3];
  const float* Wq = (const float*)d_in[4];
  const float* Wk = (const float*)d_in[5];
  const float* Wv = (const float*)d_in[6];
  const float* Wo = (const float*)d_in[7];
  float* out = (float*)d_out;

  const size_t AE = (size_t)BB * SS * DD;  // 4M elements per activation
  unsigned short* Ab  = (unsigned short*)d_ws;      // 3 x AE bf16 (24 MB)
  unsigned short* Obh = Ab;                         // aliases Ab (dead after proj)
  unsigned short* Wb  = Ab + 3 * AE;                // 4 x DD*DD bf16 (8 MB)
  unsigned short* Qb  = Wb + (size_t)4 * DD * DD;   // 8 MB each
  unsigned short* Kb  = Qb + AE;
  unsigned short* Vt  = Kb + AE;
  float* Mf = (float*)(Vt + AE);                    // BB*SS floats (16 KB)

  // 1. convert activations + weights (Wq pre-scaled by 0.125*log2e) + mask pad
  convert_kernel<<<dim3(AE / 1024, 8), 256, 0, stream>>>(
      q, k, v, Wq, Wk, Wv, Wo, mask, Ab, Wb, Mf);

  // 2. Q/K/V projections (128x128 tiles, single-buf)
  proj128_kernel<<<dim3(BB * SS / 128, DD / 128, 3), 256, 0, stream>>>(
      Ab, Wb, Qb, Kb, Vt);

  // 3. flash attention (S^T form, balanced qt mapping, head-blocked output)
  attn_kernel<<<dim3(32 * HH * BB), 256, 0, stream>>>(Qb, Kb, Vt, Mf, Obh);

  // 4. output projection (128x128 tiles, A head-blocked)
  outproj_kernel<<<dim3(BB * SS / 128, DD / 128), 256, 0, stream>>>(Obh, Wb, out);
}

// Round 8
// 221.178 us; speedup vs baseline: 1.1499x; 1.0538x over previous
//
#include <hip/hip_runtime.h>
#include <stdint.h>

// Problem constants
#define BB 2
#define SS 2048
#define DD 1024
#define HH 16
#define DHH 64

typedef __bf16 bf16_t;
typedef bf16_t bf16x8 __attribute__((ext_vector_type(8)));
typedef float f32x4 __attribute__((ext_vector_type(4)));
typedef short s16x4 __attribute__((ext_vector_type(4)));

union FragU { uint4 u; bf16x8 b; };
union Frag4U { uint2 u; s16x4 s; };

#if __has_builtin(__builtin_amdgcn_exp2f)
#define EXP2(x) __builtin_amdgcn_exp2f(x)
#else
#define EXP2(x) exp2f(x)
#endif

__device__ __forceinline__ unsigned short f2bf(float f) {
  union { float f; unsigned int u; } x; x.f = f;
  unsigned int u = x.u;
  return (unsigned short)((u + 0x7FFFu + ((u >> 16) & 1u)) >> 16);  // RNE
}

__device__ __forceinline__ uint2 pack4(float4 v) {
  uint2 r;
  r.x = (unsigned)f2bf(v.x) | ((unsigned)f2bf(v.y) << 16);
  r.y = (unsigned)f2bf(v.z) | ((unsigned)f2bf(v.w) << 16);
  return r;
}

__device__ __forceinline__ uint2 packAcc(f32x4 a) {
  uint2 r;
  r.x = (unsigned)f2bf(a[0]) | ((unsigned)f2bf(a[1]) << 16);
  r.y = (unsigned)f2bf(a[2]) | ((unsigned)f2bf(a[3]) << 16);
  return r;
}

__device__ __forceinline__ bf16x8 ldsFrag(const unsigned short* s, int idx) {
  FragU f;
  f.u = *reinterpret_cast<const uint4*>(s + idx);
  return f.b;
}

// async global -> LDS, 16 bytes per lane. LDS dest = wave-uniform base + lane*16.
__device__ __forceinline__ void gload_lds16(const unsigned short* g, unsigned short* s) {
  __builtin_amdgcn_global_load_lds(
      (const __attribute__((address_space(1))) unsigned int*)g,
      (__attribute__((address_space(3))) unsigned int*)s, 16, 0, 0);
}

#define MFMA16(a, b, c) __builtin_amdgcn_mfma_f32_16x16x32_bf16((a), (b), (c), 0, 0, 0)
#define MFMA16K16(a, b, c) __builtin_amdgcn_mfma_f32_16x16x16bf16_1k((a), (b), (c), 0, 0, 0)

// ---- fp32 -> bf16 convert: activations (z=0..2) + weights (z=3..6) + mask pad (z=7) ----
// Wq (z==3) pre-scaled by (1/8)*log2(e) (score scale + exp2-domain fold).
__global__ __launch_bounds__(256) void convert_kernel(
    const float* __restrict__ q, const float* __restrict__ k, const float* __restrict__ v,
    const float* __restrict__ Wq, const float* __restrict__ Wk,
    const float* __restrict__ Wv, const float* __restrict__ Wo,
    const int* __restrict__ mask,
    unsigned short* __restrict__ Ab, unsigned short* __restrict__ Wb,
    float* __restrict__ Mf) {
  const int z = blockIdx.y;
  if (z == 7) {  // mask -> additive pad floats (BB*SS = 4096 elements)
    if (blockIdx.x >= 4) return;
    const size_t base = (size_t)blockIdx.x * 1024 + (size_t)threadIdx.x * 4;
    int4 m4 = *reinterpret_cast<const int4*>(mask + base);
    float4 p;
    p.x = (m4.x == 0) ? -1.0e9f : 0.0f;
    p.y = (m4.y == 0) ? -1.0e9f : 0.0f;
    p.z = (m4.z == 0) ? -1.0e9f : 0.0f;
    p.w = (m4.w == 0) ? -1.0e9f : 0.0f;
    *reinterpret_cast<float4*>(Mf + base) = p;
    return;
  }
  const float* src;
  unsigned short* dst;
  float scale = 1.0f;
  if (z < 3) {
    src = (z == 0) ? q : (z == 1) ? k : v;
    dst = Ab + (size_t)z * BB * SS * DD;
  } else {
    if (blockIdx.x >= (DD * DD / 1024)) return;
    src = (z == 3) ? Wq : (z == 4) ? Wk : (z == 5) ? Wv : Wo;
    dst = Wb + (size_t)(z - 3) * DD * DD;
    if (z == 3) scale = 0.125f * 1.44269504088896f;
  }
  const size_t base = (size_t)blockIdx.x * 1024 + (size_t)threadIdx.x * 4;
  float4 val = *reinterpret_cast<const float4*>(src + base);
  val.x *= scale; val.y *= scale; val.z *= scale; val.w *= scale;
  uint2 p = pack4(val);
  *reinterpret_cast<uint2*>(dst + base) = p;
}

// ---------------- Q/K/V projections (128x128 tile, single-buf, swizzled LDS) ----------------
// z=0: Q -> [b][h][s][dh]; z=1: K -> same; z=2: V -> [b][h][dh][s]
// For z=0/1 MFMA operands are SWAPPED (C^T computed) so the in-lane r-direction
// runs along dh (contiguous) -> packed 8B stores. For z=2, unswapped r runs along s.
__global__ __launch_bounds__(256) void proj128_kernel(
    const unsigned short* __restrict__ Ab, const unsigned short* __restrict__ Wb,
    unsigned short* __restrict__ Qb, unsigned short* __restrict__ Kb,
    unsigned short* __restrict__ Vt) {
  __shared__ unsigned short sA[128 * 64];
  __shared__ unsigned short sB[128 * 64];

  const int z = blockIdx.z;
  const unsigned short* A = Ab + (size_t)z * BB * SS * DD;
  const unsigned short* W = Wb + (size_t)z * DD * DD;
  unsigned short* Out = (z == 0) ? Qb : (z == 1) ? Kb : Vt;
  const int layout = (z == 2) ? 1 : 0;

  const int t = threadIdx.x;
  const int lane = t & 63, wave = t >> 6;
  const int quad = lane >> 4, l15 = lane & 15;
  const int wr = wave >> 1, wc = wave & 1;
  const int mBase = blockIdx.x * 128, nBase = blockIdx.y * 128;

  f32x4 acc[4][4] = {};

  for (int k0 = 0; k0 < DD; k0 += 64) {
    #pragma unroll
    for (int i = 0; i < 4; ++i) {
      const int g = wave * 4 + i;
      const int row = g * 8 + (lane >> 3);
      const int oct = (lane & 7) ^ (row & 7);
      gload_lds16(A + (size_t)(mBase + row) * DD + k0 + oct * 8, &sA[g * 512]);
      gload_lds16(W + (size_t)(nBase + row) * DD + k0 + oct * 8, &sB[g * 512]);
    }
    __syncthreads();

    #pragma unroll
    for (int kk = 0; kk < 2; ++kk) {
      bf16x8 af[4], bfr[4];
      #pragma unroll
      for (int i = 0; i < 4; ++i) {
        const int row = wr * 64 + i * 16 + l15;
        af[i] = ldsFrag(sA, (row * 8 + ((kk * 4 + quad) ^ (l15 & 7))) * 8);
      }
      #pragma unroll
      for (int j = 0; j < 4; ++j) {
        const int row = wc * 64 + j * 16 + l15;
        bfr[j] = ldsFrag(sB, (row * 8 + ((kk * 4 + quad) ^ (l15 & 7))) * 8);
      }
      if (layout == 0) {
        #pragma unroll
        for (int i = 0; i < 4; ++i)
          #pragma unroll
          for (int j = 0; j < 4; ++j)
            acc[i][j] = MFMA16(bfr[j], af[i], acc[i][j]);   // C^T
      } else {
        #pragma unroll
        for (int i = 0; i < 4; ++i)
          #pragma unroll
          for (int j = 0; j < 4; ++j)
            acc[i][j] = MFMA16(af[i], bfr[j], acc[i][j]);
      }
    }
    __syncthreads();
  }

  // Epilogue: packed 8B stores
  const int b = mBase >> 11;
  const int sbase = mBase & (SS - 1);
  if (layout == 0) {
    // acc[i][j] = C^T tile: row(quad*4+r) = n (dh), col(l15) = m (s)
    #pragma unroll
    for (int i = 0; i < 4; ++i) {
      #pragma unroll
      for (int j = 0; j < 4; ++j) {
        const int s = sbase + wr * 64 + i * 16 + l15;
        const int n = nBase + wc * 64 + j * 16 + quad * 4;
        const int h = n >> 6, dh = n & (DHH - 1);
        uint2 w = packAcc(acc[i][j]);
        *reinterpret_cast<uint2*>(
            Out + ((size_t)(b * HH + h) * SS + s) * DHH + dh) = w;
      }
    }
  } else {
    // acc[i][j] = C tile: row(quad*4+r) = m (s), col(l15) = n (dh)
    #pragma unroll
    for (int i = 0; i < 4; ++i) {
      #pragma unroll
      for (int j = 0; j < 4; ++j) {
        const int s = sbase + wr * 64 + i * 16 + quad * 4;
        const int n = nBase + wc * 64 + j * 16 + l15;
        const int h = n >> 6, dh = n & (DHH - 1);
        uint2 w = packAcc(acc[i][j]);
        *reinterpret_cast<uint2*>(
            Out + ((size_t)(b * HH + h) * DHH + dh) * SS + s) = w;
      }
    }
  }
}

// ---------------- flash attention: S^T form, 64-key dbuf chunks, balanced mapping ------------
// 1024 blocks. CU-co-resident blocks (ids spaced 256) get qt sets {q,31-q,q,31-q}
// -> exactly 66 chunks per CU. XCD-grouped heads (4 heads per XCD group).
// Output head-blocked: Obh[b][h][s][dh] (dense 8KB per block).
__global__ __launch_bounds__(256, 4) void attn_kernel(
    const unsigned short* __restrict__ Qb, const unsigned short* __restrict__ Kb,
    const unsigned short* __restrict__ Vt, const float* __restrict__ Mf,
    unsigned short* __restrict__ Obh) {
  __shared__ __align__(16) unsigned short sK[2][64 * 64];
  __shared__ __align__(16) unsigned short sV[2][64 * 64];
  unsigned short* sO = &sK[0][0];  // epilogue overlay (guarded by barrier)

  const int t = threadIdx.x;
  const int lane = t & 63, wave = t >> 6;
  const int quad = lane >> 4, l15 = lane & 15;

  const int id = blockIdx.x;
  const int xcd = id & 7, rest = id >> 3;    // rest 0..127
  const int hg = rest >> 5;                  // head-in-group 0..3
  const int hd = xcd * 4 + hg;               // head-index 0..31
  const int r5 = rest & 31;
  const int qt = (hg & 1) ? (31 - r5) : r5;  // balanced across co-resident blocks
  const int b = hd >> 4;
  const int qb = qt * 64;

  const size_t headOff = (size_t)hd * SS * DHH;
  const unsigned short* Qh = Qb + headOff;  // [S][64]
  const unsigned short* Kh = Kb + headOff;  // [S][64]
  const unsigned short* Vh = Vt + headOff;  // [64][S]
  const float* Mp = Mf + b * SS;

  // Q B-frags straight from global
  bf16x8 aq[2];
  {
    const unsigned short* qp = Qh + (size_t)(qb + wave * 16 + l15) * DHH + quad * 8;
    FragU f0, f1;
    f0.u = *reinterpret_cast<const uint4*>(qp);
    f1.u = *reinterpret_cast<const uint4*>(qp + 32);
    aq[0] = f0.b; aq[1] = f1.b;
  }

  const int srow = lane >> 3, soct = lane & 7;

  // initial stage: chunk 0 -> buf 0
  #pragma unroll
  for (int i = 0; i < 2; ++i) {
    const int g = wave * 2 + i;
    const int row = g * 8 + srow;
    const int oct = soct ^ (row & 7);
    gload_lds16(Kh + (size_t)row * DHH + oct * 8, &sK[0][g * 512]);
    gload_lds16(Vh + (size_t)row * SS + oct * 8, &sV[0][g * 512]);
  }

  float m_l = -1.0e30f, l_l = 0.0f;
  f32x4 oacc[4] = {};
  const int qrow_abs = qb + wave * 16 + l15;

  for (int c = 0; c <= qt; ++c) {
    __syncthreads();  // buf[c&1] ready; buf[(c+1)&1] readers (chunk c-1) done
    if (c < qt) {
      const int c1 = (c + 1) * 64;
      const int nb = (c + 1) & 1;
      #pragma unroll
      for (int i = 0; i < 2; ++i) {
        const int g = wave * 2 + i;
        const int row = g * 8 + srow;
        const int oct = soct ^ (row & 7);
        gload_lds16(Kh + (size_t)(c1 + row) * DHH + oct * 8, &sK[nb][g * 512]);
        gload_lds16(Vh + (size_t)row * SS + c1 + oct * 8, &sV[nb][g * 512]);
      }
    }
    const int cb = c & 1;
    const int c0 = c * 64;

    // S^T tiles: sacc[j] = S^T[key=quad*4+r][q=l15], key-tile j
    f32x4 sacc[4] = {};
    #pragma unroll
    for (int kk = 0; kk < 2; ++kk) {
      #pragma unroll
      for (int j = 0; j < 4; ++j) {
        const int row = j * 16 + l15;
        bf16x8 ak = ldsFrag(sK[cb], (row * 8 + ((kk * 4 + quad) ^ (l15 & 7))) * 8);
        sacc[j] = MFMA16(ak, aq[kk], sacc[j]);
      }
    }

    // row max across quads (all values in a lane share q-row l15)
    float rm = -1.0e30f;
    #pragma unroll
    for (int j = 0; j < 4; ++j)
      rm = fmaxf(rm, fmaxf(fmaxf(sacc[j][0], sacc[j][1]), fmaxf(sacc[j][2], sacc[j][3])));
    rm = fmaxf(rm, __shfl_xor(rm, 16));
    rm = fmaxf(rm, __shfl_xor(rm, 32));
    const float mnew = fmaxf(m_l, rm);
    const float alpha = EXP2(m_l - mnew);
    m_l = mnew;

    // p = exp2(s - m + pad); pack B-frags in-register
    const bool diag = (c == qt);
    float rs = 0.0f;
    s16x4 pk[4];
    #pragma unroll
    for (int j = 0; j < 4; ++j) {
      float4 pf = *reinterpret_cast<const float4*>(Mp + c0 + j * 16 + quad * 4);
      float p0 = EXP2(sacc[j][0] - mnew + pf.x);
      float p1 = EXP2(sacc[j][1] - mnew + pf.y);
      float p2 = EXP2(sacc[j][2] - mnew + pf.z);
      float p3 = EXP2(sacc[j][3] - mnew + pf.w);
      if (diag) {
        const int key = c0 + j * 16 + quad * 4;
        p0 = (key + 0 > qrow_abs) ? 0.0f : p0;
        p1 = (key + 1 > qrow_abs) ? 0.0f : p1;
        p2 = (key + 2 > qrow_abs) ? 0.0f : p2;
        p3 = (key + 3 > qrow_abs) ? 0.0f : p3;
      }
      rs += (p0 + p1) + (p2 + p3);
      Frag4U fu;
      fu.u.x = __builtin_amdgcn_perm(__float_as_uint(p1) + 0x8000u,
                                     __float_as_uint(p0) + 0x8000u, 0x07060302u);
      fu.u.y = __builtin_amdgcn_perm(__float_as_uint(p3) + 0x8000u,
                                     __float_as_uint(p2) + 0x8000u, 0x07060302u);
      pk[j] = fu.s;
    }
    rs += __shfl_xor(rs, 16);
    rs += __shfl_xor(rs, 32);
    l_l = l_l * alpha + rs;

    #pragma unroll
    for (int jn = 0; jn < 4; ++jn)
      oacc[jn] *= alpha;

    // O^T += V^T_j * P^T_j (K=16 MFMA; pk[j] already the B operand)
    #pragma unroll
    for (int j = 0; j < 4; ++j) {
      #pragma unroll
      for (int jn = 0; jn < 4; ++jn) {
        const int row = jn * 16 + l15;
        const int oct = (2 * j + (quad >> 1)) ^ (l15 & 7);
        Frag4U av;
        av.u = *reinterpret_cast<const uint2*>(&sV[cb][(row * 8 + oct) * 8 + (quad & 1) * 4]);
        oacc[jn] = MFMA16K16(av.s, pk[j], oacc[jn]);
      }
    }
  }

  // epilogue: normalize, transpose O^T -> O via sO, dense head-blocked store
  __syncthreads();
  const float inv = 1.0f / l_l;
  #pragma unroll
  for (int jn = 0; jn < 4; ++jn) {
    uint2 w;
    w.x = (unsigned)f2bf(oacc[jn][0] * inv) | ((unsigned)f2bf(oacc[jn][1] * inv) << 16);
    w.y = (unsigned)f2bf(oacc[jn][2] * inv) | ((unsigned)f2bf(oacc[jn][3] * inv) << 16);
    *reinterpret_cast<uint2*>(&sO[(wave * 16 + l15) * 72 + jn * 16 + quad * 4]) = w;
  }
  __syncthreads();
  {
    const int row = t >> 2, seg = t & 3;
    uint4 u0 = *reinterpret_cast<const uint4*>(&sO[row * 72 + seg * 16]);
    uint4 u1 = *reinterpret_cast<const uint4*>(&sO[row * 72 + seg * 16 + 8]);
    unsigned short* dst = Obh + headOff + (size_t)(qb + row) * DHH + seg * 16;
    *reinterpret_cast<uint4*>(dst) = u0;
    *reinterpret_cast<uint4*>(dst + 8) = u1;
  }
}

// ---------------- output projection: 128x128 tile, DOUBLE-BUFFERED; A head-blocked -----------
// K-tile kt (BK=64) == head kt (DHH=64, DD/64=16=HH). Grid 256 = 1 block/CU; the
// 64KB LDS costs nothing at this occupancy, dbuf hides the staging drain.
// MFMA operands swapped (C^T) -> r-direction runs along n -> float4 stores.
__global__ __launch_bounds__(256) void outproj_kernel(
    const unsigned short* __restrict__ Obh, const unsigned short* __restrict__ Wb,
    float* __restrict__ Out) {
  __shared__ unsigned short sA[2][128 * 64];
  __shared__ unsigned short sB[2][128 * 64];

  const unsigned short* W = Wb + (size_t)3 * DD * DD;  // Wo
  const int t = threadIdx.x;
  const int lane = t & 63, wave = t >> 6;
  const int quad = lane >> 4, l15 = lane & 15;
  const int wr = wave >> 1, wc = wave & 1;
  const int mBase = blockIdx.x * 128, nBase = blockIdx.y * 128;
  const int srow = lane >> 3, soct = lane & 7;

  const int bidx = mBase >> 11;
  const int sloc = mBase & (SS - 1);
  const unsigned short* Abase = Obh + (size_t)bidx * HH * SS * DHH;

  f32x4 acc[4][4] = {};

  // stage kt=0 -> buf 0
  #pragma unroll
  for (int i = 0; i < 4; ++i) {
    const int g = wave * 4 + i;
    const int row = g * 8 + srow;
    const int oct = soct ^ (row & 7);
    gload_lds16(Abase + ((size_t)0 * SS + sloc + row) * DHH + oct * 8, &sA[0][g * 512]);
    gload_lds16(W + (size_t)(nBase + row) * DD + oct * 8, &sB[0][g * 512]);
  }

  for (int kt = 0; kt < HH; ++kt) {
    __syncthreads();
    if (kt + 1 < HH) {
      const int nb = (kt + 1) & 1;
      #pragma unroll
      for (int i = 0; i < 4; ++i) {
        const int g = wave * 4 + i;
        const int row = g * 8 + srow;
        const int oct = soct ^ (row & 7);
        gload_lds16(Abase + ((size_t)(kt + 1) * SS + sloc + row) * DHH + oct * 8,
                    &sA[nb][g * 512]);
        gload_lds16(W + (size_t)(nBase + row) * DD + (kt + 1) * 64 + oct * 8,
                    &sB[nb][g * 512]);
      }
    }
    const int cb = kt & 1;
    #pragma unroll
    for (int kk = 0; kk < 2; ++kk) {
      bf16x8 af[4], bfr[4];
      #pragma unroll
      for (int i = 0; i < 4; ++i) {
        const int row = wr * 64 + i * 16 + l15;
        af[i] = ldsFrag(sA[cb], (row * 8 + ((kk * 4 + quad) ^ (l15 & 7))) * 8);
      }
      #pragma unroll
      for (int j = 0; j < 4; ++j) {
        const int row = wc * 64 + j * 16 + l15;
        bfr[j] = ldsFrag(sB[cb], (row * 8 + ((kk * 4 + quad) ^ (l15 & 7))) * 8);
      }
      #pragma unroll
      for (int i = 0; i < 4; ++i)
        #pragma unroll
        for (int j = 0; j < 4; ++j)
          acc[i][j] = MFMA16(bfr[j], af[i], acc[i][j]);   // C^T
    }
  }

  // Epilogue: C^T tile -> row(quad*4+r)=n, col(l15)=m; float4 stores along n.
  #pragma unroll
  for (int i = 0; i < 4; ++i) {
    #pragma unroll
    for (int j = 0; j < 4; ++j) {
      const int m = mBase + wr * 64 + i * 16 + l15;
      const int n = nBase + wc * 64 + j * 16 + quad * 4;
      float4 w;
      w.x = acc[i][j][0]; w.y = acc[i][j][1];
      w.z = acc[i][j][2]; w.w = acc[i][j][3];
      *reinterpret_cast<float4*>(Out + (size_t)m * DD + n) = w;
    }
  }
}

extern "C" void kernel_launch(void* const* d_in, const int* in_sizes, int n_in,
                              void* d_out, int out_size, void* d_ws, size_t ws_size,
                              hipStream_t stream) {
  (void)in_sizes; (void)n_in; (void)out_size; (void)ws_size;
  const float* q  = (const float*)d_in[0];
  const float* k  = (const float*)d_in[1];
  const float* v  = (const float*)d_in[2];
  const int* mask = (const int*)d_in[3];
  const float* Wq = (const float*)d_in[4];
  const float* Wk = (const float*)d_in[5];
  const float* Wv = (const float*)d_in[6];
  const float* Wo = (const float*)d_in[7];
  float* out = (float*)d_out;

  const size_t AE = (size_t)BB * SS * DD;  // 4M elements per activation
  unsigned short* Ab  = (unsigned short*)d_ws;      // 3 x AE bf16 (24 MB)
  unsigned short* Obh = Ab;                         // aliases Ab (dead after proj)
  unsigned short* Wb  = Ab + 3 * AE;                // 4 x DD*DD bf16 (8 MB)
  unsigned short* Qb  = Wb + (size_t)4 * DD * DD;   // 8 MB each
  unsigned short* Kb  = Qb + AE;
  unsigned short* Vt  = Kb + AE;
  float* Mf = (float*)(Vt + AE);                    // BB*SS floats (16 KB)

  // 1. convert activations + weights (Wq pre-scaled by 0.125*log2e) + mask pad
  convert_kernel<<<dim3(AE / 1024, 8), 256, 0, stream>>>(
      q, k, v, Wq, Wk, Wv, Wo, mask, Ab, Wb, Mf);

  // 2. Q/K/V projections (128x128 tiles, single-buf, packed stores)
  proj128_kernel<<<dim3(BB * SS / 128, DD / 128, 3), 256, 0, stream>>>(
      Ab, Wb, Qb, Kb, Vt);

  // 3. flash attention (S^T form, balanced qt mapping, head-blocked output)
  attn_kernel<<<dim3(32 * HH * BB), 256, 0, stream>>>(Qb, Kb, Vt, Mf, Obh);

  // 4. output projection (128x128 tiles, dbuf, float4 stores)
  outproj_kernel<<<dim3(BB * SS / 128, DD / 128), 256, 0, stream>>>(Obh, Wb, out);
}